// Round 6
// baseline (643.690 us; speedup 1.0000x reference)
//
#include <hip/hip_runtime.h>
#include <math.h>

typedef __bf16 bf16x8 __attribute__((ext_vector_type(8)));
typedef __bf16 bf16x4 __attribute__((ext_vector_type(4)));
typedef float  f32x4  __attribute__((ext_vector_type(4)));

#define NB 8
#define NC 256
#define NHW 4096
#define NCHW_ 1048576   // 4096*256 elements per image
#define NSLOT 16

__device__ __forceinline__ float sigmoidf_(float x){ return 1.f/(1.f+expf(-x)); }
__device__ __forceinline__ float gelu_tanh(float x){
  float x3 = x*x*x;
  return 0.5f*x*(1.f+tanhf(0.7978845608028654f*(x + 0.044715f*x3)));
}

// async global->LDS 16B: per-lane global addr, LDS dest = wave-uniform base + lane*16
__device__ __forceinline__ void gload16(const void* g, void* l){
  __builtin_amdgcn_global_load_lds((const __attribute__((address_space(1))) void*)g,
                                   (__attribute__((address_space(3))) void*)l,
                                   16, 0, 0);
}

// ---------------- prep: weights reorder + (block o==0) effective BN scale/bias ----------------
__global__ void k_prep_w(const float* w0, const float* w1, const float* w2, const float* w3,
                         const float* dt_bn1s, const float* dt_bn1b,
                         const float* dt_bn2s, const float* dt_bn2b,
                         const float* c1_b, const float* bn1s, const float* bn1b,
                         const float* c2_b, const float* bn2s, const float* bn2b,
                         __bf16* wr, float* effS, float* effB){
  __shared__ float tl[9][257];
  int o = blockIdx.x; int ec = blockIdx.y; int e = ec>>2, cv = ec&3;
  int t = threadIdx.x;
  if (o == 0){
    int i = e*NC + t;
    float s, b;
    if (cv==0){ s = dt_bn1s[i]; b = dt_bn1b[i]; }
    else if (cv==1){ s = dt_bn2s[i]; b = dt_bn2b[i]; }
    else if (cv==2){ s = bn1s[i]; b = c1_b[i]*bn1s[i] + bn1b[i]; }
    else { s = bn2s[i]; b = c2_b[i]*bn2s[i] + bn2b[i]; }
    effS[ec*NC+t]=s; effB[ec*NC+t]=b;
  }
  const float* src = (cv==0)?w0 : (cv==1)?w1 : (cv==2)?w2 : w3;
  const float* sp = src + ((size_t)((e*NC + o)*NC + t))*9;
  #pragma unroll
  for (int k=0;k<9;k++) tl[k][t] = sp[k];
  __syncthreads();
  __bf16* dst = wr + (size_t)ec*589824 + (size_t)o*256;
  #pragma unroll
  for (int k=0;k<9;k++) dst[(size_t)k*65536 + t] = (__bf16)tl[k][t];
}

// ---------------- prep: x NCHW f32 -> NHWC bf16 + GAP/GMP partials ----------------
__global__ void k_prep_x(const float* x, __bf16* xh, float* gps, float* gpm){
  __shared__ float tl[32][33];
  __shared__ float rs[256], rm[256];
  int ptile = blockIdx.x, p0 = ptile*32, c0 = blockIdx.y*32, b = blockIdx.z;
  int tx = threadIdx.x&31, ty = threadIdx.x>>5;
  #pragma unroll
  for (int k=0;k<4;k++){
    int c = c0 + ty + k*8;
    tl[ty+k*8][tx] = x[(size_t)(b*NC+c)*NHW + p0 + tx];
  }
  __syncthreads();
  #pragma unroll
  for (int k=0;k<4;k++){
    int p = p0 + ty + k*8;
    xh[(size_t)b*NCHW_ + (size_t)p*NC + c0 + tx] = (__bf16)tl[tx][ty+k*8];
  }
  int c_local = threadIdx.x & 31, seg = threadIdx.x >> 5;
  float s=0.f, m=-1e30f;
  #pragma unroll
  for (int j=0;j<4;j++){ float v = tl[c_local][seg*4+j]; s+=v; m=fmaxf(m,v); }
  rs[seg*32+c_local]=s; rm[seg*32+c_local]=m;
  __syncthreads();
  if (threadIdx.x < 32){
    float ss=0.f, mm=-1e30f;
    #pragma unroll
    for (int g=0; g<8; g++){ ss += rs[g*32+threadIdx.x]; mm = fmaxf(mm, rm[g*32+threadIdx.x]); }
    gps[(size_t)(b*128+ptile)*256 + c0 + threadIdx.x] = ss;
    gpm[(size_t)(b*128+ptile)*256 + c0 + threadIdx.x] = mm;
  }
}

// ---------------- gate: partial reduce + MLP + softmax + top2 -> slot tables ----------------
__global__ void k_gate2(const float* gps, const float* gpm, const int* dom,
                        const float* dom_emb, const float* w1, const float* b1,
                        const float* lns, const float* lnb,
                        const float* w2, const float* b2,
                        int* slot_e, float* slot_w){
  __shared__ float giT[528][8];
  __shared__ float hg[8][256];
  __shared__ float stat[16];
  __shared__ float logit[8][4];
  int t = threadIdx.x;
  // reduce GAP/GMP partials (coalesced across t)
  for (int b=0;b<8;b++){
    float s=0.f, m=-1e30f;
    for (int k=0;k<128;k++){
      s += gps[(size_t)(b*128+k)*256 + t];
      m = fmaxf(m, gpm[(size_t)(b*128+k)*256 + t]);
    }
    giT[t][b]     = s/4096.f;
    giT[256+t][b] = m;
  }
  if (t<16){
    #pragma unroll
    for (int b=0;b<8;b++) giT[512+t][b] = dom_emb[dom[b]*16 + t];
  }
  __syncthreads();
  {
    float acc[8];
    float bb = b1[t];
    #pragma unroll
    for (int b=0;b<8;b++) acc[b]=bb;
    for (int k=0;k<528;k++){
      float wv = w1[k*256+t];
      #pragma unroll
      for (int b=0;b<8;b++) acc[b] += giT[k][b]*wv;
    }
    #pragma unroll
    for (int b=0;b<8;b++) hg[b][t]=acc[b];
  }
  __syncthreads();
  if (t<8){
    float mu=0.f; for(int c=0;c<256;c++) mu += hg[t][c]; mu/=256.f;
    float vr=0.f; for(int c=0;c<256;c++){ float d=hg[t][c]-mu; vr+=d*d; } vr/=256.f;
    stat[t]=mu; stat[8+t]=vr;
  }
  __syncthreads();
  for (int b=0;b<8;b++){
    float v = (hg[b][t]-stat[b])*rsqrtf(stat[8+b]+1e-5f)*lns[t]+lnb[t];
    hg[b][t] = fmaxf(v, 0.f);
  }
  __syncthreads();
  if (t<32){
    int b = t>>2, e = t&3;
    float acc = b2[e];
    for (int c=0;c<256;c++) acc += hg[b][c]*w2[c*4+e];
    logit[b][e]=acc;
  }
  __syncthreads();
  if (t==0){
    for (int b=0;b<8;b++){
      float mx = logit[b][0];
      for (int e=1;e<4;e++) mx = fmaxf(mx, logit[b][e]);
      float p[4], s=0.f;
      for (int e=0;e<4;e++){ p[e]=expf(logit[b][e]-mx); s+=p[e]; }
      for (int e=0;e<4;e++) p[e]/=s;
      int i0=0; for (int e=1;e<4;e++) if (p[e]>p[i0]) i0=e;
      int i1=-1; for (int e=0;e<4;e++){ if (e==i0) continue; if (i1<0 || p[e]>p[i1]) i1=e; }
      float den = p[i0]+p[i1];
      slot_e[2*b]   = i0; slot_w[2*b]   = p[i0]/den;
      slot_e[2*b+1] = i1; slot_w[2*b+1] = p[i1]/den;
    }
  }
}

// ---------------- MFMA implicit-GEMM conv3x3, 128x128 tile, BK=64 ----------------
// R3 structure + full-residency launch bounds: 64 VGPR + 64 AGPR = 128 regs/wave
// -> 4 waves/SIMD, 4 blocks/CU (139KB/160KB LDS), grid 1024 fully co-resident.
// ACT: 0 = linear, 1 = gelu(tanh), 2 = relu
// RED: 0 none; 1 = g1 partial; 2 = CA partials
template<int ACT, int RED>
__global__ __launch_bounds__(256,4) void k_conv(
    const __bf16* __restrict__ in0, int per_b,
    const __bf16* __restrict__ wr,  int conv_idx,
    const float* __restrict__ effS, const float* __restrict__ effB,
    const int* __restrict__ slot_e,
    const __bf16* __restrict__ zslab,
    __bf16* __restrict__ out,
    const float* __restrict__ gate_w, float* __restrict__ p_sum,
    float* __restrict__ ca_ps, float* __restrict__ ca_pm)
{
  __shared__ __bf16 smem[17408];   // 34816 B: lA[128*64] | lB[128*64]; epilogue reuses as lO[128*136]
  __bf16* lA = smem;
  __bf16* lB = smem + 8192;

  const int tid   = threadIdx.x;
  const int lin   = blockIdx.y*64 + blockIdx.x;
  const int xcd   = lin & 7;
  const int q     = lin >> 3;
  const int slot  = (xcd<<1) | (q>>6);
  const int t64   = q & 63;
  const int tileM = t64 & 1;
  const int tileN = t64 >> 1;
  const int e     = slot_e[slot];
  const int cout_base = tileM*128;
  const int pos_base  = tileN*128;      // 2 full image rows of 64
  const int lane   = tid & 63;
  const int wv     = tid >> 6;
  const int lane15 = lane & 15, quad = lane >> 4;
  const int m_off  = (wv&1)*64, n_off = (wv>>1)*64;

  const __bf16* in = in0 + (size_t)(per_b ? (slot>>1) : slot) * NCHW_;
  const __bf16* wb = wr + (size_t)(e*4 + conv_idx) * 589824;

  int ldsOff[4];
  int aOff[4];
  int bBase[4];
  int rr0[4], cl0[4];
  #pragma unroll
  for (int j=0;j<4;j++){
    int f = (wv*4+j)*64 + lane;
    int row = f>>3, ph = f&7;
    int lc = ph ^ (row&7);
    ldsOff[j] = f*8;
    aOff[j]   = (cout_base + row)*256 + lc*8;
    int gp = pos_base + row;
    rr0[j] = gp>>6; cl0[j] = gp&63;
    bBase[j] = lc*8;
  }

  f32x4 zero = {0.f,0.f,0.f,0.f};
  f32x4 acc[4][4];
  #pragma unroll
  for (int i=0;i<4;i++)
    #pragma unroll
    for (int j=0;j<4;j++) acc[i][j] = zero;

  const int ph_read = lane15 & 7;

  for (int kk=0; kk<36; ++kk){
    const int k9 = kk>>2, c0e = (kk&3)*64;
    const int k3 = k9/3;
    const int dy = k3 - 1, dx = k9 - k3*3 - 1;
    __syncthreads();
    {
      const __bf16* ws = wb + (size_t)k9*65536 + c0e;
      #pragma unroll
      for (int j=0;j<4;j++)
        gload16(ws + aOff[j], lA + ldsOff[j]);
    }
    {
      const int doff = dy*16384 + dx*256 + c0e;
      #pragma unroll
      for (int j=0;j<4;j++){
        int rr = rr0[j] + dy, cl = cl0[j] + dx;
        const __bf16* src = ((unsigned)rr < 64u && (unsigned)cl < 64u)
            ? in + (size_t)(rr0[j]*16384 + cl0[j]*256 + doff + bBase[j])
            : zslab;
        gload16(src, lB + ldsOff[j]);
      }
    }
    __syncthreads();
    #pragma unroll
    for (int s=0;s<2;s++){
      bf16x8 af[4], bfr[4];
      const int ph = (s*4 + quad) ^ ph_read;
      #pragma unroll
      for (int i=0;i<4;i++) af[i]  = *(const bf16x8*)(lA + (m_off + i*16 + lane15)*64 + ph*8);
      #pragma unroll
      for (int j=0;j<4;j++) bfr[j] = *(const bf16x8*)(lB + (n_off + j*16 + lane15)*64 + ph*8);
      #pragma unroll
      for (int i=0;i<4;i++)
        #pragma unroll
        for (int j=0;j<4;j++)
          acc[i][j] = __builtin_amdgcn_mfma_f32_16x16x32_bf16(af[i], bfr[j], acc[i][j], 0,0,0);
    }
  }
  __syncthreads();

  // epilogue: scale/bias + activation, LDS transpose, coalesced bf16 store
  const float* sS = effS + (e*4+conv_idx)*256 + cout_base;
  const float* sB = effB + (e*4+conv_idx)*256 + cout_base;
  float sc[16], bi[16];
  #pragma unroll
  for (int i=0;i<4;i++)
    #pragma unroll
    for (int r=0;r<4;r++){
      int m = m_off + i*16 + quad*4 + r;
      sc[i*4+r] = sS[m]; bi[i*4+r] = sB[m];
    }
  __bf16* lO = smem;  // [128 pos][136]
  #pragma unroll
  for (int i=0;i<4;i++){
    #pragma unroll
    for (int j=0;j<4;j++){
      int n = n_off + j*16 + lane15;
      #pragma unroll
      for (int r=0;r<4;r++){
        int m = m_off + i*16 + quad*4 + r;
        float v = acc[i][j][r]*sc[i*4+r] + bi[i*4+r];
        if (ACT==1) v = gelu_tanh(v);
        if (ACT==2) v = fmaxf(v, 0.f);
        lO[n*136 + m] = (__bf16)v;
      }
    }
  }
  __syncthreads();
  __bf16* ob = out + (size_t)slot*NCHW_;
  #pragma unroll
  for (int h=0; h<8; ++h){
    int chunk = tid + h*256;
    int prow = chunk>>4, part = chunk&15;
    *(uint4*)(ob + (size_t)(pos_base+prow)*256 + cout_base + part*8) =
      *(const uint4*)(lO + prow*136 + part*8);
  }

  if (RED==1){
    int m = tid & 127, half = tid >> 7;
    float s = 0.f;
    const __bf16* col = lO + (half*64)*136 + m;
    #pragma unroll 8
    for (int n=0;n<64;n++) s += (float)col[n*136];
    s *= gate_w[e*256 + cout_base + m];
    #pragma unroll
    for (int off=32; off; off>>=1) s += __shfl_down(s, off);
    __syncthreads();
    float* scr = (float*)smem;
    if (lane==0) scr[wv] = s;
    __syncthreads();
    if (tid==0) p_sum[slot*64 + tileN*2 + tileM] = scr[0]+scr[1]+scr[2]+scr[3];
  }
  if (RED==2){
    int m = tid & 127, half = tid >> 7;
    float s=0.f, mx=-1e30f;
    const __bf16* col = lO + (half*64)*136 + m;
    #pragma unroll 8
    for (int n=0;n<64;n++){ float v = (float)col[n*136]; s+=v; mx=fmaxf(mx,v); }
    __syncthreads();
    float* scr = (float*)smem;
    scr[half*128+m] = s; scr[256 + half*128+m] = mx;
    __syncthreads();
    if (tid<128){
      float ts = scr[tid] + scr[128+tid];
      float tm = fmaxf(scr[256+tid], scr[384+tid]);
      ca_ps[(size_t)(slot*32+tileN)*256 + cout_base + tid] = ts;
      ca_pm[(size_t)(slot*32+tileN)*256 + cout_base + tid] = tm;
    }
  }
}

// ---------------- pointwise (vectorized, g1 inline): r = x + g1*d ----------------
__global__ void k_pw_r(const __bf16* xh, const __bf16* d, const float* p_sum,
                       const float* gate_b, const int* slot_e, __bf16* r){
  int slot = blockIdx.y;
  float tot = 0.f;
  #pragma unroll
  for (int k=0;k<64;k++) tot += p_sum[slot*64+k];
  float g1 = sigmoidf_(tot/4096.f + gate_b[slot_e[slot]]);
  size_t idx8 = ((size_t)blockIdx.x*256 + threadIdx.x)*8;
  bf16x8 xv = *(const bf16x8*)(xh + (size_t)(slot>>1)*NCHW_ + idx8);
  bf16x8 dv = *(const bf16x8*)(d + (size_t)slot*NCHW_ + idx8);
  bf16x8 rv;
  #pragma unroll
  for (int k=0;k<8;k++) rv[k] = (__bf16)((float)xv[k] + g1*(float)dv[k]);
  *(bf16x8*)(r + (size_t)slot*NCHW_ + idx8) = rv;
}

// ---------------- channel attention MLP ----------------
__global__ void k_ca2(const float* ps, const float* pm, const float* w1, const float* w2,
                      const int* slot_e, float* ca){
  __shared__ float avg[256], mxs[256], hr[32];
  int slot = blockIdx.x, t = threadIdx.x;
  int e = slot_e[slot];
  float s=0.f, m=-1e30f;
  #pragma unroll
  for (int k=0;k<32;k++){
    s += ps[(size_t)(slot*32+k)*256+t];
    m = fmaxf(m, pm[(size_t)(slot*32+k)*256+t]);
  }
  avg[t]=s/4096.f; mxs[t]=m;
  __syncthreads();
  if (t<32){
    int j = t&15; int which = t>>4;
    const float* v = which? mxs : avg;
    float acc=0.f;
    for (int c=0;c<256;c++) acc += v[c]*w1[e*4096 + j*256 + c];
    hr[t] = fmaxf(acc, 0.f);
  }
  __syncthreads();
  float acc=0.f;
  #pragma unroll
  for (int j=0;j<16;j++) acc += (hr[j]+hr[16+j])*w2[e*4096 + t*16 + j];
  ca[slot*256+t] = sigmoidf_(acc);
}

// ---------------- spatial attention stage 1: mean/max over channels of h3*ca ----------------
__global__ void k_sa1(const __bf16* h3, const float* ca, float* sam){
  int slot = blockIdx.y;
  int wv = threadIdx.x>>6, lane = threadIdx.x&63;
  int p = blockIdx.x*4 + wv;
  bf16x4 hv = *(const bf16x4*)(h3 + (size_t)slot*NCHW_ + (size_t)p*256 + lane*4);
  f32x4 cv = *(const f32x4*)(ca + slot*256 + lane*4);
  float s=0.f, m=-1e30f;
  #pragma unroll
  for (int k=0;k<4;k++){ float v = (float)hv[k]*cv[k]; s+=v; m=fmaxf(m,v); }
  #pragma unroll
  for (int off=32; off; off>>=1){ s += __shfl_down(s, off); m = fmaxf(m, __shfl_down(m, off)); }
  if (lane==0){ sam[slot*8192 + p] = s/256.f; sam[slot*8192 + 4096 + p] = m; }
}

// ---------------- fused finale: inline 7x7 SA + combine + transpose to NCHW f32 ----------------
__global__ void k_fin(const __bf16* h3, const __bf16* r, const float* ca, const float* sam,
                      const float* sa_w, const int* slot_e, const float* slot_w,
                      const float* adapter, const int* dom, float* out){
  __shared__ float tl[64][33];
  __shared__ float sAtt[2][32];
  const int p0 = blockIdx.x*32, c0 = blockIdx.y*64, b = blockIdx.z;
  const int t = threadIdx.x;
  const int s0 = b*2, s1 = s0+1;
  if (t < 64){
    int pp = p0 + (t&31);
    int sl = s0 + (t>>5);
    int e = slot_e[sl];
    int y = pp>>6, x0 = pp&63;
    const float* m0 = sam + sl*8192;
    const float* m1 = m0 + 4096;
    const float* w = sa_w + e*98;
    float acc = 0.f;
    for (int ky=0;ky<7;ky++){
      int yy = y+ky-3; if ((unsigned)yy>=64u) continue;
      for (int kx=0;kx<7;kx++){
        int xx = x0+kx-3; if ((unsigned)xx>=64u) continue;
        acc += w[ky*7+kx]*m0[yy*64+xx] + w[49+ky*7+kx]*m1[yy*64+xx];
      }
    }
    sAtt[t>>5][t&31] = sigmoidf_(acc);
  }
  __syncthreads();
  const int prow = t>>3;            // 0..31
  const int cchunk = t&7;           // 0..7
  const int pos = p0 + prow;
  const int cb = c0 + cchunk*8;
  const int e0 = slot_e[s0], e1 = slot_e[s1];
  const float w0 = slot_w[s0], w1 = slot_w[s1];
  const int dm = dom[b];
  size_t o0 = (size_t)s0*NCHW_ + (size_t)pos*256 + cb;
  size_t o1 = (size_t)s1*NCHW_ + (size_t)pos*256 + cb;
  bf16x8 h0v = *(const bf16x8*)(h3+o0), h1v = *(const bf16x8*)(h3+o1);
  bf16x8 r0v = *(const bf16x8*)(r+o0),  r1v = *(const bf16x8*)(r+o1);
  float sa0 = sAtt[0][prow], sa1 = sAtt[1][prow];
  #pragma unroll
  for (int k=0;k<8;k++){
    int c = cb + k;
    float v0 = (float)h0v[k]*ca[s0*256+c]*sa0 + (float)r0v[k];
    float v1 = (float)h1v[k]*ca[s1*256+c]*sa1 + (float)r1v[k];
    float val = w0*(fmaxf(v0,0.f) + adapter[(e0*4+dm)*256+c])
              + w1*(fmaxf(v1,0.f) + adapter[(e1*4+dm)*256+c]);
    tl[cchunk*8+k][prow] = val;
  }
  __syncthreads();
  const int cl = t>>2, px = (t&3)*8;
  #pragma unroll
  for (int k=0;k<8;k++)
    out[((size_t)(b*NC + c0 + cl))*NHW + p0 + px + k] = tl[cl][px+k];
}

extern "C" void kernel_launch(void* const* d_in, const int* in_sizes, int n_in,
                              void* d_out, int out_size, void* d_ws, size_t ws_size,
                              hipStream_t stream){
  const float* x      = (const float*)d_in[0];
  const int*   dom    = (const int*)d_in[1];
  const float* g_w1   = (const float*)d_in[2];
  const float* g_b1   = (const float*)d_in[3];
  const float* ln_s   = (const float*)d_in[4];
  const float* ln_b   = (const float*)d_in[5];
  const float* g_w2   = (const float*)d_in[6];
  const float* g_b2   = (const float*)d_in[7];
  const float* dom_emb= (const float*)d_in[8];
  const float* dt_w1  = (const float*)d_in[9];
  const float* dt_bn1s= (const float*)d_in[10];
  const float* dt_bn1b= (const float*)d_in[11];
  const float* dt_w2  = (const float*)d_in[12];
  const float* dt_bn2s= (const float*)d_in[13];
  const float* dt_bn2b= (const float*)d_in[14];
  const float* gate_w = (const float*)d_in[15];
  const float* gate_b = (const float*)d_in[16];
  const float* c1_w   = (const float*)d_in[17];
  const float* c1_b   = (const float*)d_in[18];
  const float* bn1s   = (const float*)d_in[19];
  const float* bn1b   = (const float*)d_in[20];
  const float* c2_w   = (const float*)d_in[21];
  const float* c2_b   = (const float*)d_in[22];
  const float* bn2s   = (const float*)d_in[23];
  const float* bn2b   = (const float*)d_in[24];
  const float* ca_w1  = (const float*)d_in[25];
  const float* ca_w2  = (const float*)d_in[26];
  const float* sa_w   = (const float*)d_in[27];
  const float* adapter= (const float*)d_in[28];

  char* ws = (char*)d_ws;
  size_t off = 0;
  auto alloc = [&](size_t bytes)->void*{
    void* p = ws + off; off += (bytes + 255) & ~size_t(255); return p;
  };
  __bf16* wr   = (__bf16*)alloc(16ull*589824*2);   // 18.9 MB
  __bf16* xh   = (__bf16*)alloc(8ull*NCHW_*2);     // 16.8 MB
  __bf16* bufA = (__bf16*)alloc(16ull*NCHW_*2);    // 33.6 MB  h1 -> h2
  __bf16* bufB = (__bf16*)alloc(16ull*NCHW_*2);    // 33.6 MB  d -> h3
  __bf16* bufC = (__bf16*)alloc(16ull*NCHW_*2);    // 33.6 MB  r
  float* gps   = (float*)alloc(8ull*128*256*4);    // 1 MB
  float* gpm   = (float*)alloc(8ull*128*256*4);    // 1 MB
  float* effS  = (float*)alloc(4096*4);
  float* effB  = (float*)alloc(4096*4);
  int*   slot_e= (int*)alloc(64);
  float* slot_w= (float*)alloc(64);
  float* p_sum = (float*)alloc(16*64*4);
  float* ca_ps = (float*)alloc(16*32*256*4);       // 512 KB
  float* ca_pm = (float*)alloc(16*32*256*4);       // 512 KB
  float* ca    = (float*)alloc(16*256*4);
  float* sam   = (float*)alloc(16*8192*4);
  __bf16* zslab= (__bf16*)alloc(512);

  hipMemsetAsync(zslab, 0, 512, stream);

  k_prep_w<<<dim3(256,16), dim3(256), 0, stream>>>(dt_w1, dt_w2, c1_w, c2_w,
                                                   dt_bn1s, dt_bn1b, dt_bn2s, dt_bn2b,
                                                   c1_b, bn1s, bn1b, c2_b, bn2s, bn2b,
                                                   wr, effS, effB);
  k_prep_x<<<dim3(128,8,8), dim3(256), 0, stream>>>(x, xh, gps, gpm);
  k_gate2<<<dim3(1), dim3(256), 0, stream>>>(gps, gpm, dom, dom_emb, g_w1, g_b1,
                                             ln_s, ln_b, g_w2, g_b2, slot_e, slot_w);
  // expert chain on 16 active (e,b) slots
  k_conv<1,0><<<dim3(64,16), dim3(256), 0, stream>>>(xh, 1, wr, 0, effS, effB, slot_e, zslab, bufA,
                                                     gate_w, p_sum, ca_ps, ca_pm);
  k_conv<0,1><<<dim3(64,16), dim3(256), 0, stream>>>(bufA, 0, wr, 1, effS, effB, slot_e, zslab, bufB,
                                                     gate_w, p_sum, ca_ps, ca_pm);
  k_pw_r<<<dim3(512,16), dim3(256), 0, stream>>>(xh, bufB, p_sum, gate_b, slot_e, bufC);
  k_conv<2,0><<<dim3(64,16), dim3(256), 0, stream>>>(bufC, 0, wr, 2, effS, effB, slot_e, zslab, bufA,
                                                     gate_w, p_sum, ca_ps, ca_pm);
  k_conv<0,2><<<dim3(64,16), dim3(256), 0, stream>>>(bufA, 0, wr, 3, effS, effB, slot_e, zslab, bufB,
                                                     gate_w, p_sum, ca_ps, ca_pm);
  k_ca2<<<dim3(16), dim3(256), 0, stream>>>(ca_ps, ca_pm, ca_w1, ca_w2, slot_e, ca);
  k_sa1<<<dim3(1024,16), dim3(256), 0, stream>>>(bufB, ca, sam);
  k_fin<<<dim3(128,4,8), dim3(256), 0, stream>>>(bufB, bufC, ca, sam, sa_w, slot_e, slot_w,
                                                 adapter, dom, (float*)d_out);
}

// Round 7
// 609.768 us; speedup vs baseline: 1.0556x; 1.0556x over previous
//
#include <hip/hip_runtime.h>
#include <math.h>

typedef __bf16 bf16x8 __attribute__((ext_vector_type(8)));
typedef __bf16 bf16x4 __attribute__((ext_vector_type(4)));
typedef float  f32x4  __attribute__((ext_vector_type(4)));

#define NB 8
#define NC 256
#define NHW 4096
#define NCHW_ 1048576   // 4096*256 elements per image
#define NSLOT 16

__device__ __forceinline__ float sigmoidf_(float x){ return 1.f/(1.f+expf(-x)); }
__device__ __forceinline__ float gelu_tanh(float x){
  float x3 = x*x*x;
  return 0.5f*x*(1.f+tanhf(0.7978845608028654f*(x + 0.044715f*x3)));
}

// async global->LDS 16B: per-lane global addr, LDS dest = wave-uniform base + lane*16
__device__ __forceinline__ void gload16(const void* g, void* l){
  __builtin_amdgcn_global_load_lds((const __attribute__((address_space(1))) void*)g,
                                   (__attribute__((address_space(3))) void*)l,
                                   16, 0, 0);
}

// ---------------- prep: weights reorder + (block o==0) effective BN scale/bias ----------------
__global__ void k_prep_w(const float* w0, const float* w1, const float* w2, const float* w3,
                         const float* dt_bn1s, const float* dt_bn1b,
                         const float* dt_bn2s, const float* dt_bn2b,
                         const float* c1_b, const float* bn1s, const float* bn1b,
                         const float* c2_b, const float* bn2s, const float* bn2b,
                         __bf16* wr, float* effS, float* effB){
  __shared__ float tl[9][257];
  int o = blockIdx.x; int ec = blockIdx.y; int e = ec>>2, cv = ec&3;
  int t = threadIdx.x;
  if (o == 0){
    int i = e*NC + t;
    float s, b;
    if (cv==0){ s = dt_bn1s[i]; b = dt_bn1b[i]; }
    else if (cv==1){ s = dt_bn2s[i]; b = dt_bn2b[i]; }
    else if (cv==2){ s = bn1s[i]; b = c1_b[i]*bn1s[i] + bn1b[i]; }
    else { s = bn2s[i]; b = c2_b[i]*bn2s[i] + bn2b[i]; }
    effS[ec*NC+t]=s; effB[ec*NC+t]=b;
  }
  const float* src = (cv==0)?w0 : (cv==1)?w1 : (cv==2)?w2 : w3;
  const float* sp = src + ((size_t)((e*NC + o)*NC + t))*9;
  #pragma unroll
  for (int k=0;k<9;k++) tl[k][t] = sp[k];
  __syncthreads();
  __bf16* dst = wr + (size_t)ec*589824 + (size_t)o*256;
  #pragma unroll
  for (int k=0;k<9;k++) dst[(size_t)k*65536 + t] = (__bf16)tl[k][t];
}

// ---------------- prep: x NCHW f32 -> NHWC bf16 + GAP/GMP partials ----------------
__global__ void k_prep_x(const float* x, __bf16* xh, float* gps, float* gpm){
  __shared__ float tl[32][33];
  __shared__ float rs[256], rm[256];
  int ptile = blockIdx.x, p0 = ptile*32, c0 = blockIdx.y*32, b = blockIdx.z;
  int tx = threadIdx.x&31, ty = threadIdx.x>>5;
  #pragma unroll
  for (int k=0;k<4;k++){
    int c = c0 + ty + k*8;
    tl[ty+k*8][tx] = x[(size_t)(b*NC+c)*NHW + p0 + tx];
  }
  __syncthreads();
  #pragma unroll
  for (int k=0;k<4;k++){
    int p = p0 + ty + k*8;
    xh[(size_t)b*NCHW_ + (size_t)p*NC + c0 + tx] = (__bf16)tl[tx][ty+k*8];
  }
  int c_local = threadIdx.x & 31, seg = threadIdx.x >> 5;
  float s=0.f, m=-1e30f;
  #pragma unroll
  for (int j=0;j<4;j++){ float v = tl[c_local][seg*4+j]; s+=v; m=fmaxf(m,v); }
  rs[seg*32+c_local]=s; rm[seg*32+c_local]=m;
  __syncthreads();
  if (threadIdx.x < 32){
    float ss=0.f, mm=-1e30f;
    #pragma unroll
    for (int g=0; g<8; g++){ ss += rs[g*32+threadIdx.x]; mm = fmaxf(mm, rm[g*32+threadIdx.x]); }
    gps[(size_t)(b*128+ptile)*256 + c0 + threadIdx.x] = ss;
    gpm[(size_t)(b*128+ptile)*256 + c0 + threadIdx.x] = mm;
  }
}

// ---------------- gate stage 1b: reduce partials (parallel: 8 blocks) ----------------
__global__ void k_gate1b(const float* gps, const float* gpm, float* gavg, float* gmax){
  int b = blockIdx.x, c = threadIdx.x;
  float s=0.f, m=-1e30f;
  for (int k=0;k<128;k++){
    s += gps[(size_t)(b*128+k)*256 + c];
    m = fmaxf(m, gpm[(size_t)(b*128+k)*256 + c]);
  }
  gavg[b*256+c] = s/4096.f;
  gmax[b*256+c] = m;
}

// ---------------- gate stage 2: MLP + softmax + top2 -> slot tables ----------------
__global__ void k_gate2(const float* gavg, const float* gmax, const int* dom,
                        const float* dom_emb, const float* w1, const float* b1,
                        const float* lns, const float* lnb,
                        const float* w2, const float* b2,
                        int* slot_e, float* slot_w){
  __shared__ float giT[528][8];
  __shared__ float hg[8][256];
  __shared__ float stat[16];
  __shared__ float logit[8][4];
  int t = threadIdx.x;
  for (int idx=t; idx<8*528; idx+=256){
    int b = idx&7, k = idx>>3;
    float v;
    if (k<256) v = gavg[b*256+k];
    else if (k<512) v = gmax[b*256+k-256];
    else v = dom_emb[dom[b]*16 + (k-512)];
    giT[k][b]=v;
  }
  __syncthreads();
  {
    float acc[8];
    float bb = b1[t];
    #pragma unroll
    for (int b=0;b<8;b++) acc[b]=bb;
    for (int k=0;k<528;k++){
      float wv = w1[k*256+t];
      #pragma unroll
      for (int b=0;b<8;b++) acc[b] += giT[k][b]*wv;
    }
    #pragma unroll
    for (int b=0;b<8;b++) hg[b][t]=acc[b];
  }
  __syncthreads();
  if (t<8){
    float mu=0.f; for(int c=0;c<256;c++) mu += hg[t][c]; mu/=256.f;
    float vr=0.f; for(int c=0;c<256;c++){ float d=hg[t][c]-mu; vr+=d*d; } vr/=256.f;
    stat[t]=mu; stat[8+t]=vr;
  }
  __syncthreads();
  for (int b=0;b<8;b++){
    float v = (hg[b][t]-stat[b])*rsqrtf(stat[8+b]+1e-5f)*lns[t]+lnb[t];
    hg[b][t] = fmaxf(v, 0.f);
  }
  __syncthreads();
  if (t<32){
    int b = t>>2, e = t&3;
    float acc = b2[e];
    for (int c=0;c<256;c++) acc += hg[b][c]*w2[c*4+e];
    logit[b][e]=acc;
  }
  __syncthreads();
  if (t==0){
    for (int b=0;b<8;b++){
      float mx = logit[b][0];
      for (int e=1;e<4;e++) mx = fmaxf(mx, logit[b][e]);
      float p[4], s=0.f;
      for (int e=0;e<4;e++){ p[e]=expf(logit[b][e]-mx); s+=p[e]; }
      for (int e=0;e<4;e++) p[e]/=s;
      int i0=0; for (int e=1;e<4;e++) if (p[e]>p[i0]) i0=e;
      int i1=-1; for (int e=0;e<4;e++){ if (e==i0) continue; if (i1<0 || p[e]>p[i1]) i1=e; }
      float den = p[i0]+p[i1];
      slot_e[2*b]   = i0; slot_w[2*b]   = p[i0]/den;
      slot_e[2*b+1] = i1; slot_w[2*b+1] = p[i1]/den;
    }
  }
}

// ---------------- MFMA implicit-GEMM conv3x3, 128x128 tile, BK=64 ----------------
// R3 structure + full-residency launch bounds: 64 VGPR + 64 AGPR = 128 regs/wave
// -> 4 waves/SIMD, 4 blocks/CU (139KB/160KB LDS), grid 1024 fully co-resident.
// ACT: 0 = linear, 1 = gelu(tanh), 2 = relu
// RED: 0 none; 1 = g1 partial; 2 = CA partials
template<int ACT, int RED>
__global__ __launch_bounds__(256,4) void k_conv(
    const __bf16* __restrict__ in0, int per_b,
    const __bf16* __restrict__ wr,  int conv_idx,
    const float* __restrict__ effS, const float* __restrict__ effB,
    const int* __restrict__ slot_e,
    const __bf16* __restrict__ zslab,
    __bf16* __restrict__ out,
    const float* __restrict__ gate_w, float* __restrict__ p_sum,
    float* __restrict__ ca_ps, float* __restrict__ ca_pm)
{
  __shared__ __bf16 smem[17408];   // 34816 B: lA[128*64] | lB[128*64]; epilogue reuses as lO[128*136]
  __bf16* lA = smem;
  __bf16* lB = smem + 8192;

  const int tid   = threadIdx.x;
  const int lin   = blockIdx.y*64 + blockIdx.x;
  const int xcd   = lin & 7;
  const int q     = lin >> 3;
  const int slot  = (xcd<<1) | (q>>6);
  const int t64   = q & 63;
  const int tileM = t64 & 1;
  const int tileN = t64 >> 1;
  const int e     = slot_e[slot];
  const int cout_base = tileM*128;
  const int pos_base  = tileN*128;      // 2 full image rows of 64
  const int lane   = tid & 63;
  const int wv     = tid >> 6;
  const int lane15 = lane & 15, quad = lane >> 4;
  const int m_off  = (wv&1)*64, n_off = (wv>>1)*64;

  const __bf16* in = in0 + (size_t)(per_b ? (slot>>1) : slot) * NCHW_;
  const __bf16* wb = wr + (size_t)(e*4 + conv_idx) * 589824;

  int ldsOff[4];
  int aOff[4];
  int bBase[4];
  int rr0[4], cl0[4];
  #pragma unroll
  for (int j=0;j<4;j++){
    int f = (wv*4+j)*64 + lane;
    int row = f>>3, ph = f&7;
    int lc = ph ^ (row&7);
    ldsOff[j] = f*8;
    aOff[j]   = (cout_base + row)*256 + lc*8;
    int gp = pos_base + row;
    rr0[j] = gp>>6; cl0[j] = gp&63;
    bBase[j] = lc*8;
  }

  f32x4 zero = {0.f,0.f,0.f,0.f};
  f32x4 acc[4][4];
  #pragma unroll
  for (int i=0;i<4;i++)
    #pragma unroll
    for (int j=0;j<4;j++) acc[i][j] = zero;

  const int ph_read = lane15 & 7;

  for (int kk=0; kk<36; ++kk){
    const int k9 = kk>>2, c0e = (kk&3)*64;
    const int k3 = k9/3;
    const int dy = k3 - 1, dx = k9 - k3*3 - 1;
    __syncthreads();
    {
      const __bf16* ws = wb + (size_t)k9*65536 + c0e;
      #pragma unroll
      for (int j=0;j<4;j++)
        gload16(ws + aOff[j], lA + ldsOff[j]);
    }
    {
      const int doff = dy*16384 + dx*256 + c0e;
      #pragma unroll
      for (int j=0;j<4;j++){
        int rr = rr0[j] + dy, cl = cl0[j] + dx;
        const __bf16* src = ((unsigned)rr < 64u && (unsigned)cl < 64u)
            ? in + (size_t)(rr0[j]*16384 + cl0[j]*256 + doff + bBase[j])
            : zslab;
        gload16(src, lB + ldsOff[j]);
      }
    }
    __syncthreads();
    #pragma unroll
    for (int s=0;s<2;s++){
      bf16x8 af[4], bfr[4];
      const int ph = (s*4 + quad) ^ ph_read;
      #pragma unroll
      for (int i=0;i<4;i++) af[i]  = *(const bf16x8*)(lA + (m_off + i*16 + lane15)*64 + ph*8);
      #pragma unroll
      for (int j=0;j<4;j++) bfr[j] = *(const bf16x8*)(lB + (n_off + j*16 + lane15)*64 + ph*8);
      #pragma unroll
      for (int i=0;i<4;i++)
        #pragma unroll
        for (int j=0;j<4;j++)
          acc[i][j] = __builtin_amdgcn_mfma_f32_16x16x32_bf16(af[i], bfr[j], acc[i][j], 0,0,0);
    }
  }
  __syncthreads();

  // epilogue: scale/bias + activation, LDS transpose, coalesced bf16 store
  const float* sS = effS + (e*4+conv_idx)*256 + cout_base;
  const float* sB = effB + (e*4+conv_idx)*256 + cout_base;
  float sc[16], bi[16];
  #pragma unroll
  for (int i=0;i<4;i++)
    #pragma unroll
    for (int r=0;r<4;r++){
      int m = m_off + i*16 + quad*4 + r;
      sc[i*4+r] = sS[m]; bi[i*4+r] = sB[m];
    }
  __bf16* lO = smem;  // [128 pos][136]
  #pragma unroll
  for (int i=0;i<4;i++){
    #pragma unroll
    for (int j=0;j<4;j++){
      int n = n_off + j*16 + lane15;
      #pragma unroll
      for (int r=0;r<4;r++){
        int m = m_off + i*16 + quad*4 + r;
        float v = acc[i][j][r]*sc[i*4+r] + bi[i*4+r];
        if (ACT==1) v = gelu_tanh(v);
        if (ACT==2) v = fmaxf(v, 0.f);
        lO[n*136 + m] = (__bf16)v;
      }
    }
  }
  __syncthreads();
  __bf16* ob = out + (size_t)slot*NCHW_;
  #pragma unroll
  for (int h=0; h<8; ++h){
    int chunk = tid + h*256;
    int prow = chunk>>4, part = chunk&15;
    *(uint4*)(ob + (size_t)(pos_base+prow)*256 + cout_base + part*8) =
      *(const uint4*)(lO + prow*136 + part*8);
  }

  if (RED==1){
    int m = tid & 127, half = tid >> 7;
    float s = 0.f;
    const __bf16* col = lO + (half*64)*136 + m;
    #pragma unroll 8
    for (int n=0;n<64;n++) s += (float)col[n*136];
    s *= gate_w[e*256 + cout_base + m];
    #pragma unroll
    for (int off=32; off; off>>=1) s += __shfl_down(s, off);
    __syncthreads();
    float* scr = (float*)smem;
    if (lane==0) scr[wv] = s;
    __syncthreads();
    if (tid==0) p_sum[slot*64 + tileN*2 + tileM] = scr[0]+scr[1]+scr[2]+scr[3];
  }
  if (RED==2){
    int m = tid & 127, half = tid >> 7;
    float s=0.f, mx=-1e30f;
    const __bf16* col = lO + (half*64)*136 + m;
    #pragma unroll 8
    for (int n=0;n<64;n++){ float v = (float)col[n*136]; s+=v; mx=fmaxf(mx,v); }
    __syncthreads();
    float* scr = (float*)smem;
    scr[half*128+m] = s; scr[256 + half*128+m] = mx;
    __syncthreads();
    if (tid<128){
      float ts = scr[tid] + scr[128+tid];
      float tm = fmaxf(scr[256+tid], scr[384+tid]);
      ca_ps[(size_t)(slot*32+tileN)*256 + cout_base + tid] = ts;
      ca_pm[(size_t)(slot*32+tileN)*256 + cout_base + tid] = tm;
    }
  }
}

// ---------------- pointwise (vectorized, g1 inline): r = x + g1*d ----------------
__global__ void k_pw_r(const __bf16* xh, const __bf16* d, const float* p_sum,
                       const float* gate_b, const int* slot_e, __bf16* r){
  int slot = blockIdx.y;
  float tot = 0.f;
  #pragma unroll
  for (int k=0;k<64;k++) tot += p_sum[slot*64+k];
  float g1 = sigmoidf_(tot/4096.f + gate_b[slot_e[slot]]);
  size_t idx8 = ((size_t)blockIdx.x*256 + threadIdx.x)*8;
  bf16x8 xv = *(const bf16x8*)(xh + (size_t)(slot>>1)*NCHW_ + idx8);
  bf16x8 dv = *(const bf16x8*)(d + (size_t)slot*NCHW_ + idx8);
  bf16x8 rv;
  #pragma unroll
  for (int k=0;k<8;k++) rv[k] = (__bf16)((float)xv[k] + g1*(float)dv[k]);
  *(bf16x8*)(r + (size_t)slot*NCHW_ + idx8) = rv;
}

// ---------------- channel attention MLP ----------------
__global__ void k_ca2(const float* ps, const float* pm, const float* w1, const float* w2,
                      const int* slot_e, float* ca){
  __shared__ float avg[256], mxs[256], hr[32];
  int slot = blockIdx.x, t = threadIdx.x;
  int e = slot_e[slot];
  float s=0.f, m=-1e30f;
  #pragma unroll
  for (int k=0;k<32;k++){
    s += ps[(size_t)(slot*32+k)*256+t];
    m = fmaxf(m, pm[(size_t)(slot*32+k)*256+t]);
  }
  avg[t]=s/4096.f; mxs[t]=m;
  __syncthreads();
  if (t<32){
    int j = t&15; int which = t>>4;
    const float* v = which? mxs : avg;
    float acc=0.f;
    for (int c=0;c<256;c++) acc += v[c]*w1[e*4096 + j*256 + c];
    hr[t] = fmaxf(acc, 0.f);
  }
  __syncthreads();
  float acc=0.f;
  #pragma unroll
  for (int j=0;j<16;j++) acc += (hr[j]+hr[16+j])*w2[e*4096 + t*16 + j];
  ca[slot*256+t] = sigmoidf_(acc);
}

// ---------------- spatial attention stage 1: mean/max over channels of h3*ca ----------------
__global__ void k_sa1(const __bf16* h3, const float* ca, float* sam){
  int slot = blockIdx.y;
  int wv = threadIdx.x>>6, lane = threadIdx.x&63;
  int p = blockIdx.x*4 + wv;
  bf16x4 hv = *(const bf16x4*)(h3 + (size_t)slot*NCHW_ + (size_t)p*256 + lane*4);
  f32x4 cv = *(const f32x4*)(ca + slot*256 + lane*4);
  float s=0.f, m=-1e30f;
  #pragma unroll
  for (int k=0;k<4;k++){ float v = (float)hv[k]*cv[k]; s+=v; m=fmaxf(m,v); }
  #pragma unroll
  for (int off=32; off; off>>=1){ s += __shfl_down(s, off); m = fmaxf(m, __shfl_down(m, off)); }
  if (lane==0){ sam[slot*8192 + p] = s/256.f; sam[slot*8192 + 4096 + p] = m; }
}

// ---------------- fused finale: inline 7x7 SA + combine + transpose to NCHW f32 ----------------
__global__ void k_fin(const __bf16* h3, const __bf16* r, const float* ca, const float* sam,
                      const float* sa_w, const int* slot_e, const float* slot_w,
                      const float* adapter, const int* dom, float* out){
  __shared__ float tl[64][33];
  __shared__ float sAtt[2][32];
  const int p0 = blockIdx.x*32, c0 = blockIdx.y*64, b = blockIdx.z;
  const int t = threadIdx.x;
  const int s0 = b*2, s1 = s0+1;
  if (t < 64){
    int pp = p0 + (t&31);
    int sl = s0 + (t>>5);
    int e = slot_e[sl];
    int y = pp>>6, x0 = pp&63;
    const float* m0 = sam + sl*8192;
    const float* m1 = m0 + 4096;
    const float* w = sa_w + e*98;
    float acc = 0.f;
    for (int ky=0;ky<7;ky++){
      int yy = y+ky-3; if ((unsigned)yy>=64u) continue;
      for (int kx=0;kx<7;kx++){
        int xx = x0+kx-3; if ((unsigned)xx>=64u) continue;
        acc += w[ky*7+kx]*m0[yy*64+xx] + w[49+ky*7+kx]*m1[yy*64+xx];
      }
    }
    sAtt[t>>5][t&31] = sigmoidf_(acc);
  }
  __syncthreads();
  const int prow = t>>3;            // 0..31
  const int cchunk = t&7;           // 0..7
  const int pos = p0 + prow;
  const int cb = c0 + cchunk*8;
  const int e0 = slot_e[s0], e1 = slot_e[s1];
  const float w0 = slot_w[s0], w1 = slot_w[s1];
  const int dm = dom[b];
  size_t o0 = (size_t)s0*NCHW_ + (size_t)pos*256 + cb;
  size_t o1 = (size_t)s1*NCHW_ + (size_t)pos*256 + cb;
  bf16x8 h0v = *(const bf16x8*)(h3+o0), h1v = *(const bf16x8*)(h3+o1);
  bf16x8 r0v = *(const bf16x8*)(r+o0),  r1v = *(const bf16x8*)(r+o1);
  float sa0 = sAtt[0][prow], sa1 = sAtt[1][prow];
  #pragma unroll
  for (int k=0;k<8;k++){
    int c = cb + k;
    float v0 = (float)h0v[k]*ca[s0*256+c]*sa0 + (float)r0v[k];
    float v1 = (float)h1v[k]*ca[s1*256+c]*sa1 + (float)r1v[k];
    float val = w0*(fmaxf(v0,0.f) + adapter[(e0*4+dm)*256+c])
              + w1*(fmaxf(v1,0.f) + adapter[(e1*4+dm)*256+c]);
    tl[cchunk*8+k][prow] = val;
  }
  __syncthreads();
  const int cl = t>>2, px = (t&3)*8;
  #pragma unroll
  for (int k=0;k<8;k++)
    out[((size_t)(b*NC + c0 + cl))*NHW + p0 + px + k] = tl[cl][px+k];
}

extern "C" void kernel_launch(void* const* d_in, const int* in_sizes, int n_in,
                              void* d_out, int out_size, void* d_ws, size_t ws_size,
                              hipStream_t stream){
  const float* x      = (const float*)d_in[0];
  const int*   dom    = (const int*)d_in[1];
  const float* g_w1   = (const float*)d_in[2];
  const float* g_b1   = (const float*)d_in[3];
  const float* ln_s   = (const float*)d_in[4];
  const float* ln_b   = (const float*)d_in[5];
  const float* g_w2   = (const float*)d_in[6];
  const float* g_b2   = (const float*)d_in[7];
  const float* dom_emb= (const float*)d_in[8];
  const float* dt_w1  = (const float*)d_in[9];
  const float* dt_bn1s= (const float*)d_in[10];
  const float* dt_bn1b= (const float*)d_in[11];
  const float* dt_w2  = (const float*)d_in[12];
  const float* dt_bn2s= (const float*)d_in[13];
  const float* dt_bn2b= (const float*)d_in[14];
  const float* gate_w = (const float*)d_in[15];
  const float* gate_b = (const float*)d_in[16];
  const float* c1_w   = (const float*)d_in[17];
  const float* c1_b   = (const float*)d_in[18];
  const float* bn1s   = (const float*)d_in[19];
  const float* bn1b   = (const float*)d_in[20];
  const float* c2_w   = (const float*)d_in[21];
  const float* c2_b   = (const float*)d_in[22];
  const float* bn2s   = (const float*)d_in[23];
  const float* bn2b   = (const float*)d_in[24];
  const float* ca_w1  = (const float*)d_in[25];
  const float* ca_w2  = (const float*)d_in[26];
  const float* sa_w   = (const float*)d_in[27];
  const float* adapter= (const float*)d_in[28];

  char* ws = (char*)d_ws;
  size_t off = 0;
  auto alloc = [&](size_t bytes)->void*{
    void* p = ws + off; off += (bytes + 255) & ~size_t(255); return p;
  };
  __bf16* wr   = (__bf16*)alloc(16ull*589824*2);   // 18.9 MB
  __bf16* xh   = (__bf16*)alloc(8ull*NCHW_*2);     // 16.8 MB
  __bf16* bufA = (__bf16*)alloc(16ull*NCHW_*2);    // 33.6 MB  h1 -> h2
  __bf16* bufB = (__bf16*)alloc(16ull*NCHW_*2);    // 33.6 MB  d -> h3
  __bf16* bufC = (__bf16*)alloc(16ull*NCHW_*2);    // 33.6 MB  r
  float* gps   = (float*)alloc(8ull*128*256*4);    // 1 MB
  float* gpm   = (float*)alloc(8ull*128*256*4);    // 1 MB
  float* gavg  = (float*)alloc(2048*4);
  float* gmax  = (float*)alloc(2048*4);
  float* effS  = (float*)alloc(4096*4);
  float* effB  = (float*)alloc(4096*4);
  int*   slot_e= (int*)alloc(64);
  float* slot_w= (float*)alloc(64);
  float* p_sum = (float*)alloc(16*64*4);
  float* ca_ps = (float*)alloc(16*32*256*4);       // 512 KB
  float* ca_pm = (float*)alloc(16*32*256*4);       // 512 KB
  float* ca    = (float*)alloc(16*256*4);
  float* sam   = (float*)alloc(16*8192*4);
  __bf16* zslab= (__bf16*)alloc(512);

  hipMemsetAsync(zslab, 0, 512, stream);

  k_prep_w<<<dim3(256,16), dim3(256), 0, stream>>>(dt_w1, dt_w2, c1_w, c2_w,
                                                   dt_bn1s, dt_bn1b, dt_bn2s, dt_bn2b,
                                                   c1_b, bn1s, bn1b, c2_b, bn2s, bn2b,
                                                   wr, effS, effB);
  k_prep_x<<<dim3(128,8,8), dim3(256), 0, stream>>>(x, xh, gps, gpm);
  k_gate1b<<<dim3(8), dim3(256), 0, stream>>>(gps, gpm, gavg, gmax);
  k_gate2<<<dim3(1), dim3(256), 0, stream>>>(gavg, gmax, dom, dom_emb, g_w1, g_b1,
                                             ln_s, ln_b, g_w2, g_b2, slot_e, slot_w);
  // expert chain on 16 active (e,b) slots
  k_conv<1,0><<<dim3(64,16), dim3(256), 0, stream>>>(xh, 1, wr, 0, effS, effB, slot_e, zslab, bufA,
                                                     gate_w, p_sum, ca_ps, ca_pm);
  k_conv<0,1><<<dim3(64,16), dim3(256), 0, stream>>>(bufA, 0, wr, 1, effS, effB, slot_e, zslab, bufB,
                                                     gate_w, p_sum, ca_ps, ca_pm);
  k_pw_r<<<dim3(512,16), dim3(256), 0, stream>>>(xh, bufB, p_sum, gate_b, slot_e, bufC);
  k_conv<2,0><<<dim3(64,16), dim3(256), 0, stream>>>(bufC, 0, wr, 2, effS, effB, slot_e, zslab, bufA,
                                                     gate_w, p_sum, ca_ps, ca_pm);
  k_conv<0,2><<<dim3(64,16), dim3(256), 0, stream>>>(bufA, 0, wr, 3, effS, effB, slot_e, zslab, bufB,
                                                     gate_w, p_sum, ca_ps, ca_pm);
  k_ca2<<<dim3(16), dim3(256), 0, stream>>>(ca_ps, ca_pm, ca_w1, ca_w2, slot_e, ca);
  k_sa1<<<dim3(1024,16), dim3(256), 0, stream>>>(bufB, ca, sam);
  k_fin<<<dim3(128,4,8), dim3(256), 0, stream>>>(bufB, bufC, ca, sam, sa_w, slot_e, slot_w,
                                                 adapter, dom, (float*)d_out);
}